// Round 1
// baseline (1187.978 us; speedup 1.0000x reference)
//
#include <hip/hip_runtime.h>
#include <math.h>

#define B_   4
#define T_   512
#define TAU_ 512
#define L_   1024
#define DM_  1024
#define H_   16
#define D_   64

// ---------------------------------------------------------------------------
// LayerNorm over concat(memory, inputs) rows. One block per (b, l) row.
// ---------------------------------------------------------------------------
__global__ __launch_bounds__(256) void ln_concat_kernel(
    const float* __restrict__ inp, const float* __restrict__ mem,
    const float* __restrict__ gamma, const float* __restrict__ beta,
    float* __restrict__ xn) {
  int row = blockIdx.x;              // b*L + l
  int b = row >> 10, l = row & 1023;
  const float* src = (l < TAU_)
      ? mem + ((size_t)b * TAU_ + l) * DM_
      : inp + ((size_t)b * T_ + (l - TAU_)) * DM_;
  int t = threadIdx.x;
  float4 v = *(const float4*)(src + t * 4);
  float s  = v.x + v.y + v.z + v.w;
  float s2 = v.x * v.x + v.y * v.y + v.z * v.z + v.w * v.w;
#pragma unroll
  for (int off = 32; off > 0; off >>= 1) {
    s  += __shfl_down(s, off);
    s2 += __shfl_down(s2, off);
  }
  __shared__ float red[8];
  __shared__ float stat[2];
  int wid = t >> 6;
  if ((t & 63) == 0) { red[wid * 2] = s; red[wid * 2 + 1] = s2; }
  __syncthreads();
  if (t == 0) {
    float ts  = red[0] + red[2] + red[4] + red[6];
    float ts2 = red[1] + red[3] + red[5] + red[7];
    float mu  = ts * (1.0f / DM_);
    float var = ts2 * (1.0f / DM_) - mu * mu;
    stat[0] = mu;
    stat[1] = 1.0f / sqrtf(var + 1e-5f);
  }
  __syncthreads();
  float mu = stat[0], rstd = stat[1];
  float4 g  = *(const float4*)(gamma + t * 4);
  float4 be = *(const float4*)(beta  + t * 4);
  float4 o;
  o.x = (v.x - mu) * rstd * g.x + be.x;
  o.y = (v.y - mu) * rstd * g.y + be.y;
  o.z = (v.z - mu) * rstd * g.z + be.z;
  o.w = (v.w - mu) * rstd * g.w + be.w;
  *(float4*)(xn + (size_t)row * DM_ + t * 4) = o;
}

// ---------------------------------------------------------------------------
// phi[m][c]: m in [0,1024), pos = 1023-m; c<512 -> sin(pos*invf[c]),
// else cos(pos*invf[c-512]); invf[c] = 10000^(-2c/1024)
// ---------------------------------------------------------------------------
__global__ __launch_bounds__(256) void phi_kernel(float* __restrict__ phi) {
  int idx = blockIdx.x * 256 + threadIdx.x;   // 0 .. 1M-1
  int m = idx >> 10, c = idx & 1023;
  float p = (float)(1023 - m);
  int cc = (c < 512) ? c : c - 512;
  float invf = __expf(-((float)(2 * cc) * (1.0f / 1024.0f)) * 9.210340371976184f);
  float a = p * invf;
  phi[idx] = (c < 512) ? sinf(a) : cosf(a);
}

// ---------------------------------------------------------------------------
// Generic NT GEMM: C[M,N] = A[M,K] * B[N,K]^T, all row-major fp32.
// M,N multiples of 128; K multiple of 16. 256 threads, 8x8 per thread
// (split-halves layout: rows ty*4+{0..3} and 64+ty*4+{0..3}, same for cols).
// ---------------------------------------------------------------------------
#define BM 128
#define BN 128
#define BK 16
__global__ __launch_bounds__(256) void gemm_nt(
    const float* __restrict__ A, const float* __restrict__ B,
    float* __restrict__ C, int M, int N, int K) {
  __shared__ float As[BK][BM + 4];
  __shared__ float Bs[BK][BN + 4];
  int t  = threadIdx.x;
  int tx = t & 15, ty = t >> 4;
  int m0 = blockIdx.y * BM, n0 = blockIdx.x * BN;
  float acc[8][8];
#pragma unroll
  for (int i = 0; i < 8; ++i)
#pragma unroll
    for (int j = 0; j < 8; ++j) acc[i][j] = 0.0f;

  for (int kt = 0; kt < K; kt += BK) {
#pragma unroll
    for (int q = 0; q < 2; ++q) {
      int f   = t + q * 256;   // 0..511 (128 rows x 4 float4)
      int row = f >> 2;
      int c4  = (f & 3) * 4;
      float4 av = *(const float4*)(A + (size_t)(m0 + row) * K + kt + c4);
      As[c4 + 0][row] = av.x; As[c4 + 1][row] = av.y;
      As[c4 + 2][row] = av.z; As[c4 + 3][row] = av.w;
      float4 bv = *(const float4*)(B + (size_t)(n0 + row) * K + kt + c4);
      Bs[c4 + 0][row] = bv.x; Bs[c4 + 1][row] = bv.y;
      Bs[c4 + 2][row] = bv.z; Bs[c4 + 3][row] = bv.w;
    }
    __syncthreads();
#pragma unroll
    for (int kk = 0; kk < BK; ++kk) {
      float a[8], b[8];
      *(float4*)(a)     = *(const float4*)&As[kk][ty * 4];
      *(float4*)(a + 4) = *(const float4*)&As[kk][64 + ty * 4];
      *(float4*)(b)     = *(const float4*)&Bs[kk][tx * 4];
      *(float4*)(b + 4) = *(const float4*)&Bs[kk][64 + tx * 4];
#pragma unroll
      for (int i = 0; i < 8; ++i)
#pragma unroll
        for (int j = 0; j < 8; ++j) acc[i][j] += a[i] * b[j];
    }
    __syncthreads();
  }
#pragma unroll
  for (int i = 0; i < 8; ++i) {
    int m = m0 + ((i < 4) ? (ty * 4 + i) : (64 + ty * 4 + i - 4));
    float4 v0 = make_float4(acc[i][0], acc[i][1], acc[i][2], acc[i][3]);
    float4 v1 = make_float4(acc[i][4], acc[i][5], acc[i][6], acc[i][7]);
    *(float4*)(C + (size_t)m * N + n0 + tx * 4)      = v0;
    *(float4*)(C + (size_t)m * N + n0 + 64 + tx * 4) = v1;
  }
}

// ---------------------------------------------------------------------------
// Fused rel-shift flash attention.
// Block = (b, h, i-tile of 16). 256 threads.
// score[b,i,j,h] = ((q+u)·k_j + (q+v)·R[j+511-i]) / 8 for j <= 511+i... wait
//   mask: j <= TAU + i (= 512+i); R index m = j + T-1-i = j + 511 - i.
// Online softmax over j, O = sum_j p_j * v_j.
// ---------------------------------------------------------------------------
#define LDSP 68
__global__ __launch_bounds__(256) void attn_kernel(
    const float* __restrict__ qkv, const float* __restrict__ Rm,
    const float* __restrict__ uvar, const float* __restrict__ vvar,
    float* __restrict__ attn) {
  __shared__ float qu[16][LDSP];
  __shared__ float qv[16][LDSP];
  __shared__ float Ks[64][LDSP];
  __shared__ float Rs[80][LDSP];   // also reused as V tile after phase A
  __shared__ float Ss[16][LDSP];
  __shared__ float mrow[16], lrow[16], arow[16];
  float (*Vs)[LDSP] = Rs;

  int t   = threadIdx.x;
  int bid = blockIdx.x;
  int it  = bid & 31;
  int h   = (bid >> 5) & 15;
  int b   = bid >> 9;
  int i0  = it * 16;

  // stage Q (+u, +v): 16 rows x 64, one float4 per thread
  {
    int il = t >> 4, c4 = (t & 15) * 4;
    const float* qrow =
        qkv + ((size_t)(b * L_ + TAU_ + i0 + il) * 3072) + h * 64 + c4;
    float4 q4 = *(const float4*)qrow;
    float4 u4 = *(const float4*)(uvar + h * 64 + c4);
    float4 v4 = *(const float4*)(vvar + h * 64 + c4);
    float4 a, c;
    a.x = q4.x + u4.x; a.y = q4.y + u4.y; a.z = q4.z + u4.z; a.w = q4.w + u4.w;
    c.x = q4.x + v4.x; c.y = q4.y + v4.y; c.z = q4.z + v4.z; c.w = q4.w + v4.w;
    *(float4*)&qu[il][c4] = a;
    *(float4*)&qv[il][c4] = c;
  }
  if (t < 16) { mrow[t] = -__builtin_inff(); lrow[t] = 0.0f; }

  float acc0 = 0.f, acc1 = 0.f, acc2 = 0.f, acc3 = 0.f;
  int il = t >> 4;
  int u  = t & 15;
  int dbase = u * 4;
  int iglob = i0 + il;
  int jmax  = TAU_ + i0 + 15;          // max valid j in this block
  int ntiles = (jmax + 64) / 64;       // ceil((jmax+1)/64)

  for (int tile = 0; tile < ntiles; ++tile) {
    int j0 = tile * 64;
    __syncthreads();
    // stage K tile and R tile
#pragma unroll
    for (int q = 0; q < 4; ++q) {
      int f = t + q * 256;
      int jj = f >> 4, c4 = (f & 15) * 4;
      const float* base =
          qkv + ((size_t)(b * L_ + j0 + jj) * 3072) + 1024 + h * 64 + c4;
      *(float4*)&Ks[jj][c4] = *(const float4*)base;
    }
    int mbase = j0 + 496 - i0;   // = j0 + 511 - (i0+15)
#pragma unroll
    for (int q = 0; q < 5; ++q) {
      int f = t + q * 256;
      int rr = f >> 4, c4 = (f & 15) * 4;
      int m = mbase + rr;
      m = (m < 0) ? 0 : ((m > 1023) ? 1023 : m);
      *(float4*)&Rs[rr][c4] = *(const float4*)(Rm + (size_t)m * 1024 + h * 64 + c4);
    }
    __syncthreads();
    // phase A: scores -> Ss
    {
      float sA0 = 0.f, sA1 = 0.f, sA2 = 0.f, sA3 = 0.f;
      float sB0 = 0.f, sB1 = 0.f, sB2 = 0.f, sB3 = 0.f;
      int jj0 = u, jj1 = u + 16, jj2 = u + 32, jj3 = u + 48;
      int rl0 = jj0 + 15 - il, rl1 = jj1 + 15 - il,
          rl2 = jj2 + 15 - il, rl3 = jj3 + 15 - il;
#pragma unroll
      for (int d4 = 0; d4 < 16; ++d4) {
        float4 a4 = *(const float4*)&qu[il][d4 * 4];
        float4 c4 = *(const float4*)&qv[il][d4 * 4];
        float4 k0 = *(const float4*)&Ks[jj0][d4 * 4];
        float4 k1 = *(const float4*)&Ks[jj1][d4 * 4];
        float4 k2 = *(const float4*)&Ks[jj2][d4 * 4];
        float4 k3 = *(const float4*)&Ks[jj3][d4 * 4];
        float4 r0 = *(const float4*)&Rs[rl0][d4 * 4];
        float4 r1 = *(const float4*)&Rs[rl1][d4 * 4];
        float4 r2 = *(const float4*)&Rs[rl2][d4 * 4];
        float4 r3 = *(const float4*)&Rs[rl3][d4 * 4];
        sA0 += a4.x * k0.x + a4.y * k0.y + a4.z * k0.z + a4.w * k0.w;
        sA1 += a4.x * k1.x + a4.y * k1.y + a4.z * k1.z + a4.w * k1.w;
        sA2 += a4.x * k2.x + a4.y * k2.y + a4.z * k2.z + a4.w * k2.w;
        sA3 += a4.x * k3.x + a4.y * k3.y + a4.z * k3.z + a4.w * k3.w;
        sB0 += c4.x * r0.x + c4.y * r0.y + c4.z * r0.z + c4.w * r0.w;
        sB1 += c4.x * r1.x + c4.y * r1.y + c4.z * r1.z + c4.w * r1.w;
        sB2 += c4.x * r2.x + c4.y * r2.y + c4.z * r2.z + c4.w * r2.w;
        sB3 += c4.x * r3.x + c4.y * r3.y + c4.z * r3.z + c4.w * r3.w;
      }
      float ninf = -__builtin_inff();
      int lim = TAU_ + iglob;
      Ss[il][jj0] = (j0 + jj0 <= lim) ? (sA0 + sB0) * 0.125f : ninf;
      Ss[il][jj1] = (j0 + jj1 <= lim) ? (sA1 + sB1) * 0.125f : ninf;
      Ss[il][jj2] = (j0 + jj2 <= lim) ? (sA2 + sB2) * 0.125f : ninf;
      Ss[il][jj3] = (j0 + jj3 <= lim) ? (sA3 + sB3) * 0.125f : ninf;
    }
    __syncthreads();
    // stage V tile into Rs space (phase A done reading Rs)
#pragma unroll
    for (int q = 0; q < 4; ++q) {
      int f = t + q * 256;
      int jj = f >> 4, c4 = (f & 15) * 4;
      const float* base =
          qkv + ((size_t)(b * L_ + j0 + jj) * 3072) + 2048 + h * 64 + c4;
      *(float4*)&Vs[jj][c4] = *(const float4*)base;
    }
    // phase B: online softmax row update (one thread per row)
    if (t < 16) {
      float mo = mrow[t];
      float mt = mo;
#pragma unroll 8
      for (int jj = 0; jj < 64; ++jj) mt = fmaxf(mt, Ss[t][jj]);
      float alpha = __expf(mo - mt);
      float sum = 0.f;
#pragma unroll 8
      for (int jj = 0; jj < 64; ++jj) {
        float p = __expf(Ss[t][jj] - mt);
        Ss[t][jj] = p;
        sum += p;
      }
      lrow[t] = lrow[t] * alpha + sum;
      mrow[t] = mt;
      arow[t] = alpha;
    }
    __syncthreads();
    // phase C: O = O*alpha + P·V
    {
      float alpha = arow[il];
      acc0 *= alpha; acc1 *= alpha; acc2 *= alpha; acc3 *= alpha;
#pragma unroll
      for (int jj4 = 0; jj4 < 16; ++jj4) {
        float4 p4 = *(const float4*)&Ss[il][jj4 * 4];
        float4 w0 = *(const float4*)&Vs[jj4 * 4 + 0][dbase];
        float4 w1 = *(const float4*)&Vs[jj4 * 4 + 1][dbase];
        float4 w2 = *(const float4*)&Vs[jj4 * 4 + 2][dbase];
        float4 w3 = *(const float4*)&Vs[jj4 * 4 + 3][dbase];
        acc0 += p4.x * w0.x + p4.y * w1.x + p4.z * w2.x + p4.w * w3.x;
        acc1 += p4.x * w0.y + p4.y * w1.y + p4.z * w2.y + p4.w * w3.y;
        acc2 += p4.x * w0.z + p4.y * w1.z + p4.z * w2.z + p4.w * w3.z;
        acc3 += p4.x * w0.w + p4.y * w1.w + p4.z * w2.w + p4.w * w3.w;
      }
    }
  }
  float inv = 1.0f / lrow[il];
  float4 o = make_float4(acc0 * inv, acc1 * inv, acc2 * inv, acc3 * inv);
  *(float4*)(attn + ((size_t)(b * T_ + i0 + il)) * 1024 + h * 64 + dbase) = o;
}

// ---------------------------------------------------------------------------
extern "C" void kernel_launch(void* const* d_in, const int* in_sizes, int n_in,
                              void* d_out, int out_size, void* d_ws, size_t ws_size,
                              hipStream_t stream) {
  const float* inputs = (const float*)d_in[0];
  const float* memory = (const float*)d_in[1];
  const float* w_qkv  = (const float*)d_in[2];
  const float* w_pos  = (const float*)d_in[3];
  const float* w_out  = (const float*)d_in[4];
  const float* uvar   = (const float*)d_in[5];
  const float* vvar   = (const float*)d_in[6];
  const float* gamma  = (const float*)d_in[7];
  const float* beta   = (const float*)d_in[8];
  float* out = (float*)d_out;

  float* ws   = (float*)d_ws;
  float* qkv  = ws;                          // 4096*3072 floats
  float* xn   = qkv + (size_t)4096 * 3072;   // 4096*1024
  float* phi  = xn  + (size_t)4096 * 1024;   // 1024*1024
  float* Rm   = phi + (size_t)1024 * 1024;   // 1024*1024
  float* attn = xn;                          // reuse xn after QKV GEMM (2048*1024)

  ln_concat_kernel<<<B_ * L_, 256, 0, stream>>>(inputs, memory, gamma, beta, xn);
  phi_kernel<<<(L_ * DM_) / 256, 256, 0, stream>>>(phi);
  gemm_nt<<<dim3(3072 / BN, 4096 / BM), 256, 0, stream>>>(xn, w_qkv, qkv, 4096, 3072, 1024);
  gemm_nt<<<dim3(1024 / BN, 1024 / BM), 256, 0, stream>>>(phi, w_pos, Rm, 1024, 1024, 1024);
  attn_kernel<<<B_ * H_ * (T_ / 16), 256, 0, stream>>>(qkv, Rm, uvar, vvar, attn);
  gemm_nt<<<dim3(1024 / BN, 2048 / BM), 256, 0, stream>>>(attn, w_out, out, 2048, 1024, 1024);
}